// Round 1
// baseline (164.022 us; speedup 1.0000x reference)
//
#include <hip/hip_runtime.h>
#include <hip/hip_bf16.h>

// GraphLayer: B=8, K=128, D=128, TPE=64, PPE=64, HEADS=8, G=16
// d_out = [v_out (8*128*128 f32) | e_value (8*16384*128 f32)]

typedef __attribute__((ext_vector_type(8)))  short bh8;   // 8 x bf16 (as short)
typedef __attribute__((ext_vector_type(16))) float f16v;  // MFMA 32x32 accum
typedef __attribute__((ext_vector_type(4)))  float f4v;

__device__ __forceinline__ unsigned short f2bf(float f) {
  unsigned u = __builtin_bit_cast(unsigned, f);
  u += 0x7fffu + ((u >> 16) & 1u);          // RNE
  return (unsigned short)(u >> 16);
}
__device__ __forceinline__ float silu_f(float x) { return x / (1.f + __expf(-x)); }

// ---------- weight fragment prep: W[K][128] f32 -> B-frag bf16 ----------
// frag idx = ((ni*ksteps + ks)*64 + lane)*8 + jj ; col n = ni*32+(l&31), k = ks*16+(l>>5)*8+jj
__global__ void k_wfrag(const float* __restrict__ W, short* __restrict__ dst, int kdim) {
  int ksteps = kdim >> 4;
  int total = kdim * 128;
  for (int idx = blockIdx.x * blockDim.x + threadIdx.x; idx < total;
       idx += gridDim.x * blockDim.x) {
    int jj = idx & 7;
    int l  = (idx >> 3) & 63;
    int rest = idx >> 9;
    int ks = rest % ksteps;
    int ni = rest / ksteps;
    int n  = ni * 32 + (l & 31);
    int kk = ks * 16 + ((l >> 5) << 3) + jj;
    dst[idx] = (short)f2bf(W[kk * 128 + n]);
  }
}

// ---------- v = silu([v_f|p_pe|t_pe] @ W_vpe + b), rows=1024, Kdim=256 ----------
__global__ void k_vmlp(const float* __restrict__ vfeat, const float* __restrict__ ppe,
                       const float* __restrict__ tpe, const float* __restrict__ W,
                       const float* __restrict__ bias, float* __restrict__ v32,
                       unsigned short* __restrict__ vb16) {
  __shared__ float x[8][256];
  const int r0 = blockIdx.x * 8;     // global row = b*128+i
  const int b  = r0 >> 7;
  const int t  = threadIdx.x;        // 128
  #pragma unroll
  for (int rr = 0; rr < 8; ++rr) {
    int row = r0 + rr;
    x[rr][t] = vfeat[row * 128 + t];
    int c = t + 128;
    x[rr][c] = (c < 192) ? ppe[row * 64 + (c - 128)] : tpe[b * 64 + (c - 192)];
  }
  __syncthreads();
  float acc[8];
  const float bv = bias[t];
  #pragma unroll
  for (int rr = 0; rr < 8; ++rr) acc[rr] = bv;
  for (int k2 = 0; k2 < 256; ++k2) {
    float w = W[k2 * 128 + t];
    #pragma unroll
    for (int rr = 0; rr < 8; ++rr) acc[rr] += x[rr][k2] * w;
  }
  #pragma unroll
  for (int rr = 0; rr < 8; ++rr) {
    float s = silu_f(acc[rr]);
    v32[(r0 + rr) * 128 + t]  = s;
    vb16[(r0 + rr) * 128 + t] = f2bf(s);
  }
}

// ---------- q,k,self from v ----------
__global__ void k_qks(const float* __restrict__ v32,
                      const float* __restrict__ Wq, const float* __restrict__ bq,
                      const float* __restrict__ Wk, const float* __restrict__ bk,
                      const float* __restrict__ Ws, const float* __restrict__ bs,
                      float* __restrict__ q, float* __restrict__ kb,
                      float* __restrict__ sa) {
  __shared__ float x[8][128];
  const int r0 = blockIdx.x * 8;
  const int t  = threadIdx.x;
  #pragma unroll
  for (int rr = 0; rr < 8; ++rr) x[rr][t] = v32[(r0 + rr) * 128 + t];
  __syncthreads();
  float aq[8], ak[8], as_[8];
  const float bqv = bq[t], bkv = bk[t], bsv = bs[t];
  #pragma unroll
  for (int rr = 0; rr < 8; ++rr) { aq[rr] = bqv; ak[rr] = bkv; as_[rr] = bsv; }
  for (int k2 = 0; k2 < 128; ++k2) {
    float wq = Wq[k2 * 128 + t], wk = Wk[k2 * 128 + t], ws2 = Ws[k2 * 128 + t];
    #pragma unroll
    for (int rr = 0; rr < 8; ++rr) {
      float xv = x[rr][k2];
      aq[rr] += xv * wq; ak[rr] += xv * wk; as_[rr] += xv * ws2;
    }
  }
  #pragma unroll
  for (int rr = 0; rr < 8; ++rr) {
    q[(r0 + rr) * 128 + t]  = aq[rr];
    kb[(r0 + rr) * 128 + t] = ak[rr];
    sa[(r0 + rr) * 128 + t] = silu_f(as_[rr]);
  }
}

// ---------- atten[b,i,j,g] = softmax_j( sum_h q*k / sqrt(24) ) ----------
__global__ void k_atten(const float* __restrict__ q, const float* __restrict__ kmat,
                        float* __restrict__ atten) {
  __shared__ float qr[128];
  __shared__ float s[128][17];
  __shared__ float red[8][17];
  __shared__ float gmax[16];
  __shared__ float gsum[16];
  const int bi = blockIdx.x;       // b*128+i
  const int b  = bi >> 7;
  const int t  = threadIdx.x;      // 128; acts as j
  qr[t] = q[bi * 128 + t];
  __syncthreads();
  const float sc = 0.20412414523193154f;  // 1/sqrt(24)
  float loc[16];
  const float* krow = kmat + (size_t)(b * 128 + t) * 128;
  #pragma unroll
  for (int g = 0; g < 16; ++g) {
    float a = 0.f;
    #pragma unroll
    for (int h = 0; h < 8; ++h) a += qr[g * 8 + h] * krow[g * 8 + h];
    loc[g] = a * sc;
    s[t][g] = loc[g];
  }
  __syncthreads();
  { int g = t & 15, c = t >> 4;
    float m = -1e30f;
    for (int j2 = c * 16; j2 < c * 16 + 16; ++j2) m = fmaxf(m, s[j2][g]);
    red[c][g] = m; }
  __syncthreads();
  if (t < 16) {
    float m = red[0][t];
    #pragma unroll
    for (int c = 1; c < 8; ++c) m = fmaxf(m, red[c][t]);
    gmax[t] = m;
  }
  __syncthreads();
  #pragma unroll
  for (int g = 0; g < 16; ++g) { loc[g] = __expf(loc[g] - gmax[g]); s[t][g] = loc[g]; }
  __syncthreads();
  { int g = t & 15, c = t >> 4;
    float m = 0.f;
    for (int j2 = c * 16; j2 < c * 16 + 16; ++j2) m += s[j2][g];
    red[c][g] = m; }
  __syncthreads();
  if (t < 16) {
    float m = 0.f;
    #pragma unroll
    for (int c = 0; c < 8; ++c) m += red[c][t];
    gsum[t] = m;
  }
  __syncthreads();
  float* ab = atten + (size_t)bi * 2048 + (size_t)t * 16;
  #pragma unroll
  for (int g = 0; g < 16; ++g) ab[g] = loc[g] / gsum[g];
}

// ---------- dominant fused edge chain ----------
// block = (b,i); 128 j-edges; 4 waves x (32 rows x 128 cols); mfma 32x32x16 bf16
__global__ __launch_bounds__(256) void k_edge(
    const float* __restrict__ ef, const float* __restrict__ tpe,
    const unsigned short* __restrict__ vb,
    const short* __restrict__ wf1, const short* __restrict__ wf2,
    const short* __restrict__ wf3,
    const float* __restrict__ bepe, const float* __restrict__ bev1,
    const float* __restrict__ bev2, float* __restrict__ oute) {
  __shared__ unsigned short hbuf[128 * 136];  // row stride 136 shorts = 272B (odd x16B)
  const int bi  = blockIdx.x;
  const int b   = bi >> 7;
  const int tid = threadIdx.x;
  const int w   = tid >> 6;
  const int l   = tid & 63;
  const int row = w * 32 + (l & 31);          // j index (A rows)
  const int kh  = (l >> 5) << 3;              // 0 or 8
  const int cb  = l & 31;                     // C/D col base
  const int rb  = w * 32 + ((l >> 5) << 2);   // C/D row base

  f16v acc[4];
  #pragma unroll
  for (int ni = 0; ni < 4; ++ni)
    #pragma unroll
    for (int r = 0; r < 16; ++r) acc[ni][r] = 0.f;

#define MF4(WF, KSTEPS, KS, A)                                                 \
  do {                                                                         \
    const bh8* bp_ = (const bh8*)(WF);                                         \
    bh8 b0_ = bp_[(0 * (KSTEPS) + (KS)) * 64 + l];                             \
    bh8 b1_ = bp_[(1 * (KSTEPS) + (KS)) * 64 + l];                             \
    bh8 b2_ = bp_[(2 * (KSTEPS) + (KS)) * 64 + l];                             \
    bh8 b3_ = bp_[(3 * (KSTEPS) + (KS)) * 64 + l];                             \
    acc[0] = __builtin_amdgcn_mfma_f32_32x32x16_bf16((A), b0_, acc[0], 0, 0, 0); \
    acc[1] = __builtin_amdgcn_mfma_f32_32x32x16_bf16((A), b1_, acc[1], 0, 0, 0); \
    acc[2] = __builtin_amdgcn_mfma_f32_32x32x16_bf16((A), b2_, acc[2], 0, 0, 0); \
    acc[3] = __builtin_amdgcn_mfma_f32_32x32x16_bf16((A), b3_, acc[3], 0, 0, 0); \
  } while (0)

  auto epi_h = [&](const float* bias) {
    #pragma unroll
    for (int ni = 0; ni < 4; ++ni) {
      int n = ni * 32 + cb;
      float bv = bias[n];
      #pragma unroll
      for (int r = 0; r < 16; ++r) {
        int rj = rb + (r & 3) + ((r >> 2) << 3);
        hbuf[rj * 136 + n] = f2bf(silu_f(acc[ni][r] + bv));
        acc[ni][r] = 0.f;
      }
    }
  };

  // ===== layer 1: X1 = [e_f(128) | t_pe(64)], Kdim=192 (12 ksteps)
  {
    const float* efr = ef + (size_t)(bi * 128 + row) * 128;
    #pragma unroll
    for (int ks = 0; ks < 8; ++ks) {
      const float* p = efr + ks * 16 + kh;
      f4v x0 = *(const f4v*)p;
      f4v x1 = *(const f4v*)(p + 4);
      bh8 a;
      a[0] = (short)f2bf(x0[0]); a[1] = (short)f2bf(x0[1]);
      a[2] = (short)f2bf(x0[2]); a[3] = (short)f2bf(x0[3]);
      a[4] = (short)f2bf(x1[0]); a[5] = (short)f2bf(x1[1]);
      a[6] = (short)f2bf(x1[2]); a[7] = (short)f2bf(x1[3]);
      MF4(wf1, 12, ks, a);
    }
    const float* tb = tpe + b * 64;
    #pragma unroll
    for (int ks = 8; ks < 12; ++ks) {
      const float* p = tb + (ks * 16 + kh - 128);
      f4v x0 = *(const f4v*)p;
      f4v x1 = *(const f4v*)(p + 4);
      bh8 a;
      a[0] = (short)f2bf(x0[0]); a[1] = (short)f2bf(x0[1]);
      a[2] = (short)f2bf(x0[2]); a[3] = (short)f2bf(x0[3]);
      a[4] = (short)f2bf(x1[0]); a[5] = (short)f2bf(x1[1]);
      a[6] = (short)f2bf(x1[2]); a[7] = (short)f2bf(x1[3]);
      MF4(wf1, 12, ks, a);
    }
  }
  epi_h(bepe);          // h1 -> hbuf (same-wave rows only)
  __syncthreads();

  // ===== layer 2: X2 = [v_i(128) | v_j(128) | h1(128)], Kdim=384 (24 ksteps)
  {
    const unsigned short* vi = vb + (size_t)bi * 128;
    const unsigned short* vj = vb + (size_t)(b * 128 + row) * 128;
    #pragma unroll
    for (int ks = 0; ks < 8; ++ks) {
      bh8 a = *(const bh8*)(vi + ks * 16 + kh);
      MF4(wf2, 24, ks, a);
    }
    #pragma unroll
    for (int ks = 8; ks < 16; ++ks) {
      bh8 a = *(const bh8*)(vj + (ks * 16 + kh - 128));
      MF4(wf2, 24, ks, a);
    }
    #pragma unroll
    for (int ks = 16; ks < 24; ++ks) {
      bh8 a = *(const bh8*)(&hbuf[row * 136 + (ks * 16 + kh - 256)]);
      MF4(wf2, 24, ks, a);
    }
  }
  __syncthreads();      // all h1 reads done before overwrite
  epi_h(bev1);          // h2 -> hbuf
  __syncthreads();

  // ===== layer 3: e_value = h2 @ W_ev2 + b, Kdim=128 (8 ksteps)
  #pragma unroll
  for (int ks = 0; ks < 8; ++ks) {
    bh8 a = *(const bh8*)(&hbuf[row * 136 + ks * 16 + kh]);
    MF4(wf3, 8, ks, a);
  }
  #pragma unroll
  for (int ni = 0; ni < 4; ++ni) {
    int n = ni * 32 + cb;
    float bv = bev2[n];
    #pragma unroll
    for (int r = 0; r < 16; ++r) {
      int rj = rb + (r & 3) + ((r >> 2) << 3);
      oute[(size_t)(bi * 128 + rj) * 128 + n] = acc[ni][r] + bv;
    }
  }
#undef MF4
}

// ---------- agg + self residual -> vf ----------
__global__ void k_agg(const float* __restrict__ atten, const float* __restrict__ ev,
                      const float* __restrict__ sa, float* __restrict__ vfb) {
  __shared__ float att[128][16];
  const int bi = blockIdx.x;
  const int t  = threadIdx.x;   // 128, acts as e
  const float* ab = atten + (size_t)bi * 2048;
  for (int idx = t; idx < 2048; idx += 128) att[idx >> 4][idx & 15] = ab[idx];
  __syncthreads();
  const int g = t >> 3;
  const float* evb = ev + (size_t)bi * 16384 + t;
  float a0 = 0.f, a1 = 0.f, a2 = 0.f, a3 = 0.f;
  for (int j2 = 0; j2 < 128; j2 += 4) {
    a0 += att[j2 + 0][g] * evb[(j2 + 0) * 128];
    a1 += att[j2 + 1][g] * evb[(j2 + 1) * 128];
    a2 += att[j2 + 2][g] * evb[(j2 + 2) * 128];
    a3 += att[j2 + 3][g] * evb[(j2 + 3) * 128];
  }
  vfb[(size_t)bi * 128 + t] = (a0 + a1) + (a2 + a3) + sa[(size_t)bi * 128 + t];
}

// ---------- max-pool over i (2 stage) ----------
__global__ void k_pool1(const float* __restrict__ vfb, float* __restrict__ pm) {
  const int b = blockIdx.x >> 3, c = blockIdx.x & 7;
  const int t = threadIdx.x;
  float m = -1e30f;
  for (int i2 = c * 16; i2 < c * 16 + 16; ++i2)
    m = fmaxf(m, vfb[(size_t)(b * 128 + i2) * 128 + t]);
  pm[(size_t)blockIdx.x * 128 + t] = m;
}
__global__ void k_pool2(const float* __restrict__ pm, float* __restrict__ pool) {
  const int b = blockIdx.x;
  const int t = threadIdx.x;
  float m = -1e30f;
  #pragma unroll
  for (int c = 0; c < 8; ++c) m = fmaxf(m, pm[(size_t)(b * 8 + c) * 128 + t]);
  pool[b * 128 + t] = m;
}

// ---------- out MLP: v_out = silu([vf|pool] @ W_out + b) ----------
__global__ void k_out(const float* __restrict__ vfb, const float* __restrict__ pool,
                      const float* __restrict__ W, const float* __restrict__ bias,
                      float* __restrict__ vout) {
  __shared__ float x[8][256];
  const int r0 = blockIdx.x * 8;
  const int b  = r0 >> 7;
  const int t  = threadIdx.x;
  #pragma unroll
  for (int rr = 0; rr < 8; ++rr) {
    x[rr][t]       = vfb[(r0 + rr) * 128 + t];
    x[rr][t + 128] = pool[b * 128 + t];
  }
  __syncthreads();
  float acc[8];
  const float bv = bias[t];
  #pragma unroll
  for (int rr = 0; rr < 8; ++rr) acc[rr] = bv;
  for (int k2 = 0; k2 < 256; ++k2) {
    float w = W[k2 * 128 + t];
    #pragma unroll
    for (int rr = 0; rr < 8; ++rr) acc[rr] += x[rr][k2] * w;
  }
  #pragma unroll
  for (int rr = 0; rr < 8; ++rr) vout[(r0 + rr) * 128 + t] = silu_f(acc[rr]);
}

extern "C" void kernel_launch(void* const* d_in, const int* in_sizes, int n_in,
                              void* d_out, int out_size, void* d_ws, size_t ws_size,
                              hipStream_t stream) {
  const float* v_f    = (const float*)d_in[0];
  const float* e_f    = (const float*)d_in[1];
  const float* p_pe   = (const float*)d_in[2];
  const float* t_pe   = (const float*)d_in[3];
  const float* W_vpe  = (const float*)d_in[4];
  const float* b_vpe  = (const float*)d_in[5];
  const float* W_epe  = (const float*)d_in[6];
  const float* b_epe  = (const float*)d_in[7];
  const float* W_ev1  = (const float*)d_in[8];
  const float* b_ev1  = (const float*)d_in[9];
  const float* W_ev2  = (const float*)d_in[10];
  const float* b_ev2  = (const float*)d_in[11];
  const float* W_q    = (const float*)d_in[12];
  const float* b_q    = (const float*)d_in[13];
  const float* W_k    = (const float*)d_in[14];
  const float* b_k    = (const float*)d_in[15];
  const float* W_self = (const float*)d_in[16];
  const float* b_self = (const float*)d_in[17];
  const float* W_out  = (const float*)d_in[18];
  const float* b_out  = (const float*)d_in[19];

  char* ws = (char*)d_ws;
  float*          v32   = (float*)(ws + 0);
  unsigned short* vb16  = (unsigned short*)(ws + 524288);
  float*          qbuf  = (float*)(ws + 786432);
  float*          kbuf  = (float*)(ws + 1310720);
  float*          sabuf = (float*)(ws + 1835008);
  float*          vfbuf = (float*)(ws + 2359296);
  float*          pool  = (float*)(ws + 2883584);
  short*          wf1   = (short*)(ws + 2887680);
  short*          wf2   = (short*)(ws + 2936832);
  short*          wf3   = (short*)(ws + 3035136);
  float*          atten = (float*)(ws + 3067904);
  float*          pmax  = (float*)(ws + 11456512);  // total 11.5 MB

  float* v_out = (float*)d_out;
  float* out_e = (float*)d_out + 131072;

  k_wfrag<<<96, 256, 0, stream>>>(W_epe, wf1, 192);
  k_wfrag<<<192, 256, 0, stream>>>(W_ev1, wf2, 384);
  k_wfrag<<<64, 256, 0, stream>>>(W_ev2, wf3, 128);
  k_vmlp<<<128, 128, 0, stream>>>(v_f, p_pe, t_pe, W_vpe, b_vpe, v32, vb16);
  k_qks<<<128, 128, 0, stream>>>(v32, W_q, b_q, W_k, b_k, W_self, b_self,
                                 qbuf, kbuf, sabuf);
  k_atten<<<1024, 128, 0, stream>>>(qbuf, kbuf, atten);
  k_edge<<<1024, 256, 0, stream>>>(e_f, t_pe, vb16, wf1, wf2, wf3,
                                   b_epe, b_ev1, b_ev2, out_e);
  k_agg<<<1024, 128, 0, stream>>>(atten, out_e, sabuf, vfbuf);
  k_pool1<<<64, 128, 0, stream>>>(vfbuf, pmax);
  k_pool2<<<8, 128, 0, stream>>>(pmax, pool);
  k_out<<<128, 128, 0, stream>>>(vfbuf, pool, W_out, b_out, v_out);
}

// Round 2
// 151.410 us; speedup vs baseline: 1.0833x; 1.0833x over previous
//
#include <hip/hip_runtime.h>
#include <hip/hip_bf16.h>

// GraphLayer: B=8, K=128, D=128, TPE=64, PPE=64, HEADS=8, G=16
// d_out = [v_out (8*128*128 f32) | e_value (8*16384*128 f32)]

typedef __attribute__((ext_vector_type(8)))  short bh8;   // 8 x bf16 (as short)
typedef __attribute__((ext_vector_type(16))) float f16v;  // MFMA 32x32 accum
typedef __attribute__((ext_vector_type(4)))  float f4v;

__device__ __forceinline__ unsigned short f2bf(float f) {
  unsigned u = __builtin_bit_cast(unsigned, f);
  u += 0x7fffu + ((u >> 16) & 1u);          // RNE
  return (unsigned short)(u >> 16);
}
__device__ __forceinline__ float silu_f(float x) { return x / (1.f + __expf(-x)); }

// ---------- weight fragment prep (3 weights, one launch) ----------
// frag idx = ((ni*ksteps + ks)*64 + lane)*8 + jj ; col n = ni*32+(l&31), k = ks*16+(l>>5)*8+jj
__device__ __forceinline__ void wfrag_work(const float* __restrict__ W,
                                           short* __restrict__ dst, int kdim,
                                           int blk, int nblk) {
  int ksteps = kdim >> 4;
  int total  = kdim * 128;
  for (int idx = blk * 256 + threadIdx.x; idx < total; idx += nblk * 256) {
    int jj = idx & 7;
    int l  = (idx >> 3) & 63;
    int rest = idx >> 9;
    int ks = rest % ksteps;
    int ni = rest / ksteps;
    int n  = ni * 32 + (l & 31);
    int kk = ks * 16 + ((l >> 5) << 3) + jj;
    dst[idx] = (short)f2bf(W[kk * 128 + n]);
  }
}
__global__ void k_wfrag3(const float* __restrict__ W1, short* __restrict__ d1,
                         const float* __restrict__ W2, short* __restrict__ d2,
                         const float* __restrict__ W3, short* __restrict__ d3) {
  int blk = blockIdx.x;
  if (blk < 96)       wfrag_work(W1, d1, 192, blk, 96);
  else if (blk < 288) wfrag_work(W2, d2, 384, blk - 96, 192);
  else                wfrag_work(W3, d3, 128, blk - 288, 64);
}

// ---------- fused node MLPs: v = silu(x@Wv+b); q,k,self from v ----------
__global__ __launch_bounds__(128) void k_node(
    const float* __restrict__ vfeat, const float* __restrict__ ppe,
    const float* __restrict__ tpe, const float* __restrict__ Wv,
    const float* __restrict__ bv, const float* __restrict__ Wq,
    const float* __restrict__ bq, const float* __restrict__ Wk,
    const float* __restrict__ bk, const float* __restrict__ Ws,
    const float* __restrict__ bs, unsigned short* __restrict__ vb16,
    float* __restrict__ q, float* __restrict__ kb, float* __restrict__ sa) {
  __shared__ float x[4][256];
  __shared__ float xv[4][128];
  const int r0 = blockIdx.x * 4;
  const int b  = r0 >> 7;
  const int t  = threadIdx.x;
  #pragma unroll
  for (int rr = 0; rr < 4; ++rr) {
    int row = r0 + rr;
    x[rr][t] = vfeat[row * 128 + t];
    int c = t + 128;
    x[rr][c] = (c < 192) ? ppe[row * 64 + (c - 128)] : tpe[b * 64 + (c - 192)];
  }
  __syncthreads();
  float av[4];
  const float bvv = bv[t];
  #pragma unroll
  for (int rr = 0; rr < 4; ++rr) av[rr] = bvv;
  for (int k4 = 0; k4 < 256; k4 += 4) {
    f4v xx0 = *(const f4v*)&x[0][k4];
    f4v xx1 = *(const f4v*)&x[1][k4];
    f4v xx2 = *(const f4v*)&x[2][k4];
    f4v xx3 = *(const f4v*)&x[3][k4];
    #pragma unroll
    for (int u = 0; u < 4; ++u) {
      float w = Wv[(k4 + u) * 128 + t];
      av[0] += xx0[u] * w; av[1] += xx1[u] * w;
      av[2] += xx2[u] * w; av[3] += xx3[u] * w;
    }
  }
  #pragma unroll
  for (int rr = 0; rr < 4; ++rr) {
    float s = silu_f(av[rr]);
    vb16[(r0 + rr) * 128 + t] = f2bf(s);
    xv[rr][t] = s;
  }
  __syncthreads();
  float aq[4], ak[4], as_[4];
  const float bqv = bq[t], bkv = bk[t], bsv = bs[t];
  #pragma unroll
  for (int rr = 0; rr < 4; ++rr) { aq[rr] = bqv; ak[rr] = bkv; as_[rr] = bsv; }
  for (int k4 = 0; k4 < 128; k4 += 4) {
    f4v xx0 = *(const f4v*)&xv[0][k4];
    f4v xx1 = *(const f4v*)&xv[1][k4];
    f4v xx2 = *(const f4v*)&xv[2][k4];
    f4v xx3 = *(const f4v*)&xv[3][k4];
    #pragma unroll
    for (int u = 0; u < 4; ++u) {
      float wq = Wq[(k4 + u) * 128 + t];
      float wk = Wk[(k4 + u) * 128 + t];
      float ws2 = Ws[(k4 + u) * 128 + t];
      aq[0] += xx0[u] * wq; aq[1] += xx1[u] * wq; aq[2] += xx2[u] * wq; aq[3] += xx3[u] * wq;
      ak[0] += xx0[u] * wk; ak[1] += xx1[u] * wk; ak[2] += xx2[u] * wk; ak[3] += xx3[u] * wk;
      as_[0] += xx0[u] * ws2; as_[1] += xx1[u] * ws2; as_[2] += xx2[u] * ws2; as_[3] += xx3[u] * ws2;
    }
  }
  #pragma unroll
  for (int rr = 0; rr < 4; ++rr) {
    q[(r0 + rr) * 128 + t]  = aq[rr];
    kb[(r0 + rr) * 128 + t] = ak[rr];
    sa[(r0 + rr) * 128 + t] = silu_f(as_[rr]);
  }
}

// ---------- atten[b,i,j,g] = softmax_j( sum_h q*k / sqrt(24) ) ----------
__global__ void k_atten(const float* __restrict__ q, const float* __restrict__ kmat,
                        float* __restrict__ atten) {
  __shared__ float qr[128];
  __shared__ float s[128][17];
  __shared__ float red[8][17];
  __shared__ float gmax[16];
  __shared__ float gsum[16];
  const int bi = blockIdx.x;       // b*128+i
  const int b  = bi >> 7;
  const int t  = threadIdx.x;      // 128; acts as j
  qr[t] = q[bi * 128 + t];
  __syncthreads();
  const float sc = 0.20412414523193154f;  // 1/sqrt(24)
  float loc[16];
  const float* krow = kmat + (size_t)(b * 128 + t) * 128;
  #pragma unroll
  for (int g = 0; g < 16; ++g) {
    f4v k0 = *(const f4v*)&krow[g * 8];
    f4v k1 = *(const f4v*)&krow[g * 8 + 4];
    float a = 0.f;
    #pragma unroll
    for (int h = 0; h < 4; ++h) a += qr[g * 8 + h] * k0[h] + qr[g * 8 + 4 + h] * k1[h];
    loc[g] = a * sc;
    s[t][g] = loc[g];
  }
  __syncthreads();
  { int g = t & 15, c = t >> 4;
    float m = -1e30f;
    for (int j2 = c * 16; j2 < c * 16 + 16; ++j2) m = fmaxf(m, s[j2][g]);
    red[c][g] = m; }
  __syncthreads();
  if (t < 16) {
    float m = red[0][t];
    #pragma unroll
    for (int c = 1; c < 8; ++c) m = fmaxf(m, red[c][t]);
    gmax[t] = m;
  }
  __syncthreads();
  #pragma unroll
  for (int g = 0; g < 16; ++g) { loc[g] = __expf(loc[g] - gmax[g]); s[t][g] = loc[g]; }
  __syncthreads();
  { int g = t & 15, c = t >> 4;
    float m = 0.f;
    for (int j2 = c * 16; j2 < c * 16 + 16; ++j2) m += s[j2][g];
    red[c][g] = m; }
  __syncthreads();
  if (t < 16) {
    float m = 0.f;
    #pragma unroll
    for (int c = 0; c < 8; ++c) m += red[c][t];
    gsum[t] = m;
  }
  __syncthreads();
  float* ab = atten + (size_t)bi * 2048 + (size_t)t * 16;
  #pragma unroll
  for (int g = 0; g < 16; ++g) ab[g] = loc[g] / gsum[g];
}

// ---------- dominant fused edge chain + in-block aggregation ----------
// block = (b,i); 128 j-edges; 4 waves x (32 rows x 128 cols); mfma 32x32x16 bf16
__global__ __launch_bounds__(256, 4) void k_edge(
    const float* __restrict__ ef, const float* __restrict__ tpe,
    const unsigned short* __restrict__ vb,
    const short* __restrict__ wf1, const short* __restrict__ wf2,
    const short* __restrict__ wf3,
    const float* __restrict__ bepe, const float* __restrict__ bev1,
    const float* __restrict__ bev2, const float* __restrict__ atten,
    const float* __restrict__ sab, float* __restrict__ oute,
    float* __restrict__ vfb) {
  __shared__ __align__(16) unsigned short hbuf[128 * 136];  // 272B row stride (17x16B)
  const int bi  = blockIdx.x;
  const int b   = bi >> 7;
  const int tid = threadIdx.x;
  const int w   = tid >> 6;
  const int l   = tid & 63;
  const int row = w * 32 + (l & 31);          // j index (A rows)
  const int kh  = (l >> 5) << 3;              // 0 or 8
  const int cb  = l & 31;                     // C/D col base
  const int rb  = w * 32 + ((l >> 5) << 2);   // C/D row base

  f16v acc[4];
  #pragma unroll
  for (int ni = 0; ni < 4; ++ni)
    #pragma unroll
    for (int r = 0; r < 16; ++r) acc[ni][r] = 0.f;

  const bh8* bp1 = (const bh8*)wf1;
  const bh8* bp2 = (const bh8*)wf2;
  const bh8* bp3 = (const bh8*)wf3;

#define LDB(dst, bp, KSTEPS, KS)                       \
  do {                                                 \
    dst[0] = (bp)[(0 * (KSTEPS) + (KS)) * 64 + l];     \
    dst[1] = (bp)[(1 * (KSTEPS) + (KS)) * 64 + l];     \
    dst[2] = (bp)[(2 * (KSTEPS) + (KS)) * 64 + l];     \
    dst[3] = (bp)[(3 * (KSTEPS) + (KS)) * 64 + l];     \
  } while (0)
#define MFMA4(c0, c1, c2, c3, A)                                              \
  do {                                                                        \
    acc[0] = __builtin_amdgcn_mfma_f32_32x32x16_bf16((A), c0, acc[0], 0, 0, 0); \
    acc[1] = __builtin_amdgcn_mfma_f32_32x32x16_bf16((A), c1, acc[1], 0, 0, 0); \
    acc[2] = __builtin_amdgcn_mfma_f32_32x32x16_bf16((A), c2, acc[2], 0, 0, 0); \
    acc[3] = __builtin_amdgcn_mfma_f32_32x32x16_bf16((A), c3, acc[3], 0, 0, 0); \
  } while (0)

  auto epi_h = [&](const float* bias) {
    #pragma unroll
    for (int ni = 0; ni < 4; ++ni) {
      int n = ni * 32 + cb;
      float bv = bias[n];
      #pragma unroll
      for (int r = 0; r < 16; ++r) {
        int rj = rb + (r & 3) + ((r >> 2) << 3);
        hbuf[rj * 136 + n] = f2bf(silu_f(acc[ni][r] + bv));
        acc[ni][r] = 0.f;
      }
    }
  };

  const float* efr = ef + (size_t)(bi * 128 + row) * 128;
  const float* tb  = tpe + b * 64;
  auto loadA1 = [&](int ks) -> bh8 {
    const float* p = (ks < 8) ? (efr + ks * 16 + kh) : (tb + ks * 16 + kh - 128);
    f4v x0 = *(const f4v*)p;
    f4v x1 = *(const f4v*)(p + 4);
    bh8 a;
    a[0] = (short)f2bf(x0[0]); a[1] = (short)f2bf(x0[1]);
    a[2] = (short)f2bf(x0[2]); a[3] = (short)f2bf(x0[3]);
    a[4] = (short)f2bf(x1[0]); a[5] = (short)f2bf(x1[1]);
    a[6] = (short)f2bf(x1[2]); a[7] = (short)f2bf(x1[3]);
    return a;
  };

  bh8 fb[2][4];
  bh8 aA[2];

  // ===== layer 1: X1 = [e_f(128) | t_pe(64)], Kdim=192 (12 ksteps)
  LDB(fb[0], bp1, 12, 0); LDB(fb[1], bp1, 12, 1);
  aA[0] = loadA1(0); aA[1] = loadA1(1);
  #pragma unroll
  for (int ks = 0; ks < 12; ++ks) {
    bh8 c0 = fb[ks & 1][0], c1 = fb[ks & 1][1], c2 = fb[ks & 1][2], c3 = fb[ks & 1][3];
    bh8 ca = aA[ks & 1];
    if (ks + 2 < 12) { LDB(fb[ks & 1], bp1, 12, ks + 2); aA[ks & 1] = loadA1(ks + 2); }
    MFMA4(c0, c1, c2, c3, ca);
  }

  const unsigned short* vi = vb + (size_t)bi * 128;
  const unsigned short* vj = vb + (size_t)(b * 128 + row) * 128;
  // prefetch layer-2 first steps, then epilogue (hbuf rows are per-wave: no barrier)
  LDB(fb[0], bp2, 24, 0); LDB(fb[1], bp2, 24, 1);
  bh8 a20 = *(const bh8*)(vi + kh);
  bh8 a21 = *(const bh8*)(vi + 16 + kh);
  epi_h(bepe);   // h1 -> hbuf (same-wave rows only)

  // ===== layer 2: X2 = [v_i(128) | v_j(128) | h1(128)], Kdim=384 (24 ksteps)
  auto loadA2 = [&](int ks) -> bh8 {
    if (ks < 8)       return *(const bh8*)(vi + ks * 16 + kh);
    else if (ks < 16) return *(const bh8*)(vj + ks * 16 + kh - 128);
    else              return *(const bh8*)(&hbuf[row * 136 + ks * 16 + kh - 256]);
  };
  aA[0] = a20; aA[1] = a21;
  #pragma unroll
  for (int ks = 0; ks < 24; ++ks) {
    bh8 c0 = fb[ks & 1][0], c1 = fb[ks & 1][1], c2 = fb[ks & 1][2], c3 = fb[ks & 1][3];
    bh8 ca = aA[ks & 1];
    if (ks + 2 < 24) { LDB(fb[ks & 1], bp2, 24, ks + 2); aA[ks & 1] = loadA2(ks + 2); }
    MFMA4(c0, c1, c2, c3, ca);
  }

  LDB(fb[0], bp3, 8, 0); LDB(fb[1], bp3, 8, 1);
  epi_h(bev1);   // h2 -> hbuf (same-wave rows only)

  // ===== layer 3: e_value = h2 @ W_ev2 + b, Kdim=128 (8 ksteps)
  auto loadA3 = [&](int ks) -> bh8 {
    return *(const bh8*)(&hbuf[row * 136 + ks * 16 + kh]);
  };
  aA[0] = loadA3(0); aA[1] = loadA3(1);
  #pragma unroll
  for (int ks = 0; ks < 8; ++ks) {
    bh8 c0 = fb[ks & 1][0], c1 = fb[ks & 1][1], c2 = fb[ks & 1][2], c3 = fb[ks & 1][3];
    bh8 ca = aA[ks & 1];
    if (ks + 2 < 8) { LDB(fb[ks & 1], bp3, 8, ks + 2); aA[ks & 1] = loadA3(ks + 2); }
    MFMA4(c0, c1, c2, c3, ca);
  }

  // ===== epilogue: bias + e_value store
  #pragma unroll
  for (int ni = 0; ni < 4; ++ni) {
    int n = ni * 32 + cb;
    float bv = bev2[n];
    #pragma unroll
    for (int r = 0; r < 16; ++r) {
      int rj = rb + (r & 3) + ((r >> 2) << 3);
      acc[ni][r] += bv;
      oute[(size_t)(bi * 128 + rj) * 128 + n] = acc[ni][r];
    }
  }

  // ===== in-block aggregation: vf[n] = sum_j atten[j][n>>3]*ev[j][n] + silu_self
  __syncthreads();                       // all layer-3 hbuf reads complete
  float* attf = (float*)hbuf;            // [j][gl][ni] transposed, 2048 f32
  float* aggl = attf + 2048;             // [4 waves][128]
  const float* ap = atten + (size_t)bi * 2048;
  #pragma unroll
  for (int u = 0; u < 8; ++u) {
    int idx = u * 256 + tid;
    float v = ap[idx];
    int j2 = idx >> 4, g = idx & 15;
    attf[j2 * 16 + (g & 3) * 4 + (g >> 2)] = v;
  }
  float sav = 0.f;
  if (tid < 128) sav = sab[(size_t)bi * 128 + tid];
  __syncthreads();
  float p0 = 0.f, p1 = 0.f, p2 = 0.f, p3 = 0.f;
  const int gl = (l & 31) >> 3;
  #pragma unroll
  for (int r = 0; r < 16; ++r) {
    int rj = rb + (r & 3) + ((r >> 2) << 3);
    f4v av = *(const f4v*)&attf[rj * 16 + gl * 4];
    p0 += av[0] * acc[0][r]; p1 += av[1] * acc[1][r];
    p2 += av[2] * acc[2][r]; p3 += av[3] * acc[3][r];
  }
  p0 += __shfl_xor(p0, 32); p1 += __shfl_xor(p1, 32);
  p2 += __shfl_xor(p2, 32); p3 += __shfl_xor(p3, 32);
  if (l < 32) {
    aggl[w * 128 +  0 + l] = p0;
    aggl[w * 128 + 32 + l] = p1;
    aggl[w * 128 + 64 + l] = p2;
    aggl[w * 128 + 96 + l] = p3;
  }
  __syncthreads();
  if (tid < 128) {
    vfb[(size_t)bi * 128 + tid] =
        aggl[tid] + aggl[128 + tid] + aggl[256 + tid] + aggl[384 + tid] + sav;
  }
#undef LDB
#undef MFMA4
}

// ---------- max-pool over i ----------
__global__ void k_pool(const float* __restrict__ vfb, float* __restrict__ pool) {
  const int b = blockIdx.x, t = threadIdx.x;
  float m0 = -1e30f, m1 = -1e30f, m2 = -1e30f, m3 = -1e30f;
  for (int i = 0; i < 128; i += 4) {
    m0 = fmaxf(m0, vfb[(size_t)(b * 128 + i + 0) * 128 + t]);
    m1 = fmaxf(m1, vfb[(size_t)(b * 128 + i + 1) * 128 + t]);
    m2 = fmaxf(m2, vfb[(size_t)(b * 128 + i + 2) * 128 + t]);
    m3 = fmaxf(m3, vfb[(size_t)(b * 128 + i + 3) * 128 + t]);
  }
  pool[b * 128 + t] = fmaxf(fmaxf(m0, m1), fmaxf(m2, m3));
}

// ---------- out MLP: v_out = silu([vf|pool] @ W_out + b) ----------
__global__ __launch_bounds__(128) void k_out(
    const float* __restrict__ vfb, const float* __restrict__ pool,
    const float* __restrict__ W, const float* __restrict__ bias,
    float* __restrict__ vout) {
  __shared__ float x[4][256];
  const int r0 = blockIdx.x * 4;
  const int b  = r0 >> 7;
  const int t  = threadIdx.x;
  #pragma unroll
  for (int rr = 0; rr < 4; ++rr) {
    x[rr][t]       = vfb[(r0 + rr) * 128 + t];
    x[rr][t + 128] = pool[b * 128 + t];
  }
  __syncthreads();
  float acc[4];
  const float bv = bias[t];
  #pragma unroll
  for (int rr = 0; rr < 4; ++rr) acc[rr] = bv;
  for (int k4 = 0; k4 < 256; k4 += 4) {
    f4v xx0 = *(const f4v*)&x[0][k4];
    f4v xx1 = *(const f4v*)&x[1][k4];
    f4v xx2 = *(const f4v*)&x[2][k4];
    f4v xx3 = *(const f4v*)&x[3][k4];
    #pragma unroll
    for (int u = 0; u < 4; ++u) {
      float w = W[(k4 + u) * 128 + t];
      acc[0] += xx0[u] * w; acc[1] += xx1[u] * w;
      acc[2] += xx2[u] * w; acc[3] += xx3[u] * w;
    }
  }
  #pragma unroll
  for (int rr = 0; rr < 4; ++rr) vout[(r0 + rr) * 128 + t] = silu_f(acc[rr]);
}

extern "C" void kernel_launch(void* const* d_in, const int* in_sizes, int n_in,
                              void* d_out, int out_size, void* d_ws, size_t ws_size,
                              hipStream_t stream) {
  const float* v_f    = (const float*)d_in[0];
  const float* e_f    = (const float*)d_in[1];
  const float* p_pe   = (const float*)d_in[2];
  const float* t_pe   = (const float*)d_in[3];
  const float* W_vpe  = (const float*)d_in[4];
  const float* b_vpe  = (const float*)d_in[5];
  const float* W_epe  = (const float*)d_in[6];
  const float* b_epe  = (const float*)d_in[7];
  const float* W_ev1  = (const float*)d_in[8];
  const float* b_ev1  = (const float*)d_in[9];
  const float* W_ev2  = (const float*)d_in[10];
  const float* b_ev2  = (const float*)d_in[11];
  const float* W_q    = (const float*)d_in[12];
  const float* b_q    = (const float*)d_in[13];
  const float* W_k    = (const float*)d_in[14];
  const float* b_k    = (const float*)d_in[15];
  const float* W_self = (const float*)d_in[16];
  const float* b_self = (const float*)d_in[17];
  const float* W_out  = (const float*)d_in[18];
  const float* b_out  = (const float*)d_in[19];

  char* ws = (char*)d_ws;
  unsigned short* vb16  = (unsigned short*)(ws + 0);        // 262144
  float*          qbuf  = (float*)(ws + 262144);            // 524288
  float*          kbuf  = (float*)(ws + 786432);            // 524288
  float*          sabuf = (float*)(ws + 1310720);           // 524288
  float*          vfbuf = (float*)(ws + 1835008);           // 524288
  float*          pool  = (float*)(ws + 2359296);           // 4096
  short*          wf1   = (short*)(ws + 2363392);           // 49152
  short*          wf2   = (short*)(ws + 2412544);           // 98304
  short*          wf3   = (short*)(ws + 2510848);           // 32768
  float*          atten = (float*)(ws + 2543616);           // 8388608 -> 10.93MB

  float* v_out = (float*)d_out;
  float* out_e = (float*)d_out + 131072;

  k_wfrag3<<<352, 256, 0, stream>>>(W_epe, wf1, W_ev1, wf2, W_ev2, wf3);
  k_node<<<256, 128, 0, stream>>>(v_f, p_pe, t_pe, W_vpe, b_vpe, W_q, b_q,
                                  W_k, b_k, W_self, b_self, vb16, qbuf, kbuf, sabuf);
  k_atten<<<1024, 128, 0, stream>>>(qbuf, kbuf, atten);
  k_edge<<<1024, 256, 0, stream>>>(e_f, t_pe, vb16, wf1, wf2, wf3,
                                   b_epe, b_ev1, b_ev2, atten, sabuf, out_e, vfbuf);
  k_pool<<<8, 128, 0, stream>>>(vfbuf, pool);
  k_out<<<256, 128, 0, stream>>>(vfbuf, pool, W_out, b_out, v_out);
}

// Round 3
// 118.700 us; speedup vs baseline: 1.3818x; 1.2756x over previous
//
#include <hip/hip_runtime.h>
#include <hip/hip_bf16.h>

// GraphLayer: B=8, K=128, D=128, TPE=64, PPE=64, HEADS=8, G=16
// d_out = [v_out (8*128*128 f32) | e_value (8*16384*128 f32)]

typedef __attribute__((ext_vector_type(8)))  short bh8;   // 8 x bf16 (as short)
typedef __attribute__((ext_vector_type(16))) float f16v;  // MFMA 32x32 accum
typedef __attribute__((ext_vector_type(4)))  float f4v;

__device__ __forceinline__ unsigned short f2bf(float f) {
  unsigned u = __builtin_bit_cast(unsigned, f);
  u += 0x7fffu + ((u >> 16) & 1u);          // RNE
  return (unsigned short)(u >> 16);
}
__device__ __forceinline__ float silu_f(float x) {
  float e = __builtin_amdgcn_exp2f(x * -1.44269504088896f);   // e^-x
  return x * __builtin_amdgcn_rcpf(1.f + e);
}
__device__ __forceinline__ bh8 cvt8(f4v x, f4v y) {
  bh8 a;
  a[0] = (short)f2bf(x[0]); a[1] = (short)f2bf(x[1]);
  a[2] = (short)f2bf(x[2]); a[3] = (short)f2bf(x[3]);
  a[4] = (short)f2bf(y[0]); a[5] = (short)f2bf(y[1]);
  a[6] = (short)f2bf(y[2]); a[7] = (short)f2bf(y[3]);
  return a;
}
typedef const __attribute__((address_space(1))) unsigned int gq_t;
typedef __attribute__((address_space(3))) unsigned int lq_t;
__device__ __forceinline__ void gload_lds16(const void* g, void* l) {
  // dest is wave-uniform base; HW adds lane*16. src is per-lane.
  __builtin_amdgcn_global_load_lds((gq_t*)g, (lq_t*)l, 16, 0, 0);
}

// ---------- weight fragment prep (3 weights, one launch) ----------
// frag idx = ((ni*ksteps + ks)*64 + lane)*8 + jj ; col n = ni*32+(l&31), k = ks*16+(l>>5)*8+jj
__device__ __forceinline__ void wfrag_work(const float* __restrict__ W,
                                           short* __restrict__ dst, int kdim,
                                           int blk, int nblk) {
  int ksteps = kdim >> 4;
  int total  = kdim * 128;
  for (int idx = blk * 256 + threadIdx.x; idx < total; idx += nblk * 256) {
    int jj = idx & 7;
    int l  = (idx >> 3) & 63;
    int rest = idx >> 9;
    int ks = rest % ksteps;
    int ni = rest / ksteps;
    int n  = ni * 32 + (l & 31);
    int kk = ks * 16 + ((l >> 5) << 3) + jj;
    dst[idx] = (short)f2bf(W[kk * 128 + n]);
  }
}
__global__ void k_wfrag3(const float* __restrict__ W1, short* __restrict__ d1,
                         const float* __restrict__ W2, short* __restrict__ d2,
                         const float* __restrict__ W3, short* __restrict__ d3) {
  int blk = blockIdx.x;
  if (blk < 96)       wfrag_work(W1, d1, 192, blk, 96);
  else if (blk < 288) wfrag_work(W2, d2, 384, blk - 96, 192);
  else                wfrag_work(W3, d3, 128, blk - 288, 64);
}

// ---------- fused node MLPs: v = silu(x@Wv+b); q,k,self from v ----------
__global__ __launch_bounds__(128) void k_node(
    const float* __restrict__ vfeat, const float* __restrict__ ppe,
    const float* __restrict__ tpe, const float* __restrict__ Wv,
    const float* __restrict__ bv, const float* __restrict__ Wq,
    const float* __restrict__ bq, const float* __restrict__ Wk,
    const float* __restrict__ bk, const float* __restrict__ Ws,
    const float* __restrict__ bs, unsigned short* __restrict__ vb16,
    float* __restrict__ q, float* __restrict__ kb, float* __restrict__ sa) {
  __shared__ float x[4][256];
  __shared__ float xv[4][128];
  const int r0 = blockIdx.x * 4;
  const int b  = r0 >> 7;
  const int t  = threadIdx.x;
  #pragma unroll
  for (int rr = 0; rr < 4; ++rr) {
    int row = r0 + rr;
    x[rr][t] = vfeat[row * 128 + t];
    int c = t + 128;
    x[rr][c] = (c < 192) ? ppe[row * 64 + (c - 128)] : tpe[b * 64 + (c - 192)];
  }
  __syncthreads();
  float av[4];
  const float bvv = bv[t];
  #pragma unroll
  for (int rr = 0; rr < 4; ++rr) av[rr] = bvv;
  for (int k4 = 0; k4 < 256; k4 += 4) {
    f4v xx0 = *(const f4v*)&x[0][k4];
    f4v xx1 = *(const f4v*)&x[1][k4];
    f4v xx2 = *(const f4v*)&x[2][k4];
    f4v xx3 = *(const f4v*)&x[3][k4];
    #pragma unroll
    for (int u = 0; u < 4; ++u) {
      float w = Wv[(k4 + u) * 128 + t];
      av[0] += xx0[u] * w; av[1] += xx1[u] * w;
      av[2] += xx2[u] * w; av[3] += xx3[u] * w;
    }
  }
  #pragma unroll
  for (int rr = 0; rr < 4; ++rr) {
    float s = silu_f(av[rr]);
    vb16[(r0 + rr) * 128 + t] = f2bf(s);
    xv[rr][t] = s;
  }
  __syncthreads();
  float aq[4], ak[4], as_[4];
  const float bqv = bq[t], bkv = bk[t], bsv = bs[t];
  #pragma unroll
  for (int rr = 0; rr < 4; ++rr) { aq[rr] = bqv; ak[rr] = bkv; as_[rr] = bsv; }
  for (int k4 = 0; k4 < 128; k4 += 4) {
    f4v xx0 = *(const f4v*)&xv[0][k4];
    f4v xx1 = *(const f4v*)&xv[1][k4];
    f4v xx2 = *(const f4v*)&xv[2][k4];
    f4v xx3 = *(const f4v*)&xv[3][k4];
    #pragma unroll
    for (int u = 0; u < 4; ++u) {
      float wq = Wq[(k4 + u) * 128 + t];
      float wk = Wk[(k4 + u) * 128 + t];
      float ws2 = Ws[(k4 + u) * 128 + t];
      aq[0] += xx0[u] * wq; aq[1] += xx1[u] * wq; aq[2] += xx2[u] * wq; aq[3] += xx3[u] * wq;
      ak[0] += xx0[u] * wk; ak[1] += xx1[u] * wk; ak[2] += xx2[u] * wk; ak[3] += xx3[u] * wk;
      as_[0] += xx0[u] * ws2; as_[1] += xx1[u] * ws2; as_[2] += xx2[u] * ws2; as_[3] += xx3[u] * ws2;
    }
  }
  #pragma unroll
  for (int rr = 0; rr < 4; ++rr) {
    q[(r0 + rr) * 128 + t]  = aq[rr];
    kb[(r0 + rr) * 128 + t] = ak[rr];
    sa[(r0 + rr) * 128 + t] = silu_f(as_[rr]);
  }
}

// ---------- atten[b,i,j,g] = softmax_j( sum_h q*k / sqrt(24) ) ----------
__global__ void k_atten(const float* __restrict__ q, const float* __restrict__ kmat,
                        float* __restrict__ atten) {
  __shared__ float qr[128];
  __shared__ float s[128][17];
  __shared__ float red[8][17];
  __shared__ float gmax[16];
  __shared__ float gsum[16];
  const int bi = blockIdx.x;       // b*128+i
  const int b  = bi >> 7;
  const int t  = threadIdx.x;      // 128; acts as j
  qr[t] = q[bi * 128 + t];
  __syncthreads();
  const float sc = 0.20412414523193154f;  // 1/sqrt(24)
  float loc[16];
  const float* krow = kmat + (size_t)(b * 128 + t) * 128;
  #pragma unroll
  for (int g = 0; g < 16; ++g) {
    f4v k0 = *(const f4v*)&krow[g * 8];
    f4v k1 = *(const f4v*)&krow[g * 8 + 4];
    float a = 0.f;
    #pragma unroll
    for (int h = 0; h < 4; ++h) a += qr[g * 8 + h] * k0[h] + qr[g * 8 + 4 + h] * k1[h];
    loc[g] = a * sc;
    s[t][g] = loc[g];
  }
  __syncthreads();
  { int g = t & 15, c = t >> 4;
    float m = -1e30f;
    for (int j2 = c * 16; j2 < c * 16 + 16; ++j2) m = fmaxf(m, s[j2][g]);
    red[c][g] = m; }
  __syncthreads();
  if (t < 16) {
    float m = red[0][t];
    #pragma unroll
    for (int c = 1; c < 8; ++c) m = fmaxf(m, red[c][t]);
    gmax[t] = m;
  }
  __syncthreads();
  #pragma unroll
  for (int g = 0; g < 16; ++g) {
    loc[g] = __builtin_amdgcn_exp2f((loc[g] - gmax[g]) * 1.44269504088896f);
    s[t][g] = loc[g];
  }
  __syncthreads();
  { int g = t & 15, c = t >> 4;
    float m = 0.f;
    for (int j2 = c * 16; j2 < c * 16 + 16; ++j2) m += s[j2][g];
    red[c][g] = m; }
  __syncthreads();
  if (t < 16) {
    float m = 0.f;
    #pragma unroll
    for (int c = 0; c < 8; ++c) m += red[c][t];
    gsum[t] = m;
  }
  __syncthreads();
  float* ab = atten + (size_t)bi * 2048 + (size_t)t * 16;
  #pragma unroll
  for (int g = 0; g < 16; ++g) ab[g] = loc[g] * __builtin_amdgcn_rcpf(gsum[g]);
}

// ---------- dominant fused edge chain + in-block aggregation ----------
// block = (b,i); 128 j-edges; 4 waves x (32 rows x 128 cols); mfma 32x32x16 bf16
// Weights LDS-staged in 2-kstep chunks (8KB), double-buffered, shared by 4 waves.
__global__ __launch_bounds__(256) void k_edge(
    const float* __restrict__ ef, const float* __restrict__ tpe,
    const unsigned short* __restrict__ vb,
    const short* __restrict__ wf1, const short* __restrict__ wf2,
    const short* __restrict__ wf3,
    const float* __restrict__ bepe, const float* __restrict__ bev1,
    const float* __restrict__ bev2, const float* __restrict__ atten,
    const float* __restrict__ sab, float* __restrict__ oute,
    float* __restrict__ vfb) {
  __shared__ __align__(16) unsigned short wbuf0[4096];      // 8KB chunk buffer
  __shared__ __align__(16) unsigned short wbuf1[4096];      // 8KB chunk buffer
  __shared__ __align__(16) unsigned short hbuf[128 * 136];  // 34816B, 272B row stride
  const int bi  = blockIdx.x;
  const int b   = bi >> 7;
  const int tid = threadIdx.x;
  const int w   = tid >> 6;
  const int l   = tid & 63;
  const int row = w * 32 + (l & 31);          // j index (A rows)
  const int kh  = (l >> 5) << 3;              // 0 or 8
  const int cb  = l & 31;                     // C/D col base
  const int rb  = w * 32 + ((l >> 5) << 2);   // C/D row base

  f16v acc[4];
  #pragma unroll
  for (int ni = 0; ni < 4; ++ni)
    #pragma unroll
    for (int r = 0; r < 16; ++r) acc[ni][r] = 0.f;

  // stage one 2-kstep chunk (8 frags x 1KB); per wave 2 global_load_lds of 16B/lane
  auto stage2 = [&](const short* wfp, int KST, int kc, unsigned short* dstb) {
    #pragma unroll
    for (int it = 0; it < 2; ++it) {
      int g   = it * 4 + w;          // 8 groups over 4 waves x 2 issues
      int ni  = g & 3, kso = g >> 2;
      const short* src = wfp + ((size_t)(ni * KST + kc * 2 + kso) * 64 + l) * 8;
      gload_lds16(src, dstb + g * 512);   // wave-uniform dest; HW adds l*16B
    }
  };
  // compute one chunk: 2 ksteps x 4 ni
  auto compute2 = [&](const unsigned short* ws2, bh8 aa, bh8 ab) {
    #pragma unroll
    for (int ni = 0; ni < 4; ++ni) {
      bh8 b0 = *(const bh8*)&ws2[ni * 512 + l * 8];
      acc[ni] = __builtin_amdgcn_mfma_f32_32x32x16_bf16(aa, b0, acc[ni], 0, 0, 0);
    }
    #pragma unroll
    for (int ni = 0; ni < 4; ++ni) {
      bh8 b1 = *(const bh8*)&ws2[(4 + ni) * 512 + l * 8];
      acc[ni] = __builtin_amdgcn_mfma_f32_32x32x16_bf16(ab, b1, acc[ni], 0, 0, 0);
    }
  };
  auto epi_h = [&](const float* bias) {
    #pragma unroll
    for (int ni = 0; ni < 4; ++ni) {
      int n = ni * 32 + cb;
      float bv = bias[n];
      #pragma unroll
      for (int r = 0; r < 16; ++r) {
        int rj = rb + (r & 3) + ((r >> 2) << 3);
        hbuf[rj * 136 + n] = f2bf(silu_f(acc[ni][r] + bv));
        acc[ni][r] = 0.f;
      }
    }
  };

  const float* efr = ef + (size_t)(bi * 128 + row) * 128;
  const float* tb  = tpe + b * 64;
  const unsigned short* vi = vb + (size_t)bi * 128;
  const unsigned short* vj = vb + (size_t)(b * 128 + row) * 128;

  bh8 a0c, a1c, a0n, a1n;
  f4v pN[4];

  // ===== prologue: stage L1 chunk0, load A ks0,1
  stage2(wf1, 12, 0, wbuf0);
  pN[0] = *(const f4v*)(efr + kh);      pN[1] = *(const f4v*)(efr + kh + 4);
  pN[2] = *(const f4v*)(efr + 16 + kh); pN[3] = *(const f4v*)(efr + 16 + kh + 4);
  a0c = cvt8(pN[0], pN[1]); a1c = cvt8(pN[2], pN[3]);
  __syncthreads();

  // ===== layer 1: Kdim=192, 6 chunks. A: ks0-7 e_f, ks8-11 t_pe
#define L1_PREF(c)                                                            \
  { int ks = 2 * (c) + 2;                                                     \
    const float* s0 = (ks < 8) ? efr + ks * 16 + kh : tb + ks * 16 + kh - 128; \
    const float* s1 = (ks < 7) ? efr + (ks + 1) * 16 + kh : tb + (ks + 1) * 16 + kh - 128; \
    pN[0] = *(const f4v*)s0; pN[1] = *(const f4v*)(s0 + 4);                   \
    pN[2] = *(const f4v*)s1; pN[3] = *(const f4v*)(s1 + 4); }
  #pragma unroll
  for (int h = 0; h < 3; ++h) {
    { const int c = 2 * h;
      if (c < 5) stage2(wf1, 12, c + 1, wbuf1); else stage2(wf2, 24, 0, wbuf1);
      if (c < 5) L1_PREF(c);
      compute2(wbuf0, a0c, a1c);
      if (c < 5) { a0n = cvt8(pN[0], pN[1]); a1n = cvt8(pN[2], pN[3]); }
      __syncthreads();
    }
    { const int c = 2 * h + 1;
      if (c < 5) stage2(wf1, 12, c + 1, wbuf0); else stage2(wf2, 24, 0, wbuf0);
      if (c < 5) L1_PREF(c);
      compute2(wbuf1, a0n, a1n);
      if (c < 5) { a0c = cvt8(pN[0], pN[1]); a1c = cvt8(pN[2], pN[3]); }
      __syncthreads();
    }
  }
#undef L1_PREF

  // ===== L2 prologue: A ks0,1 (v_i broadcast), then h1 epilogue (per-wave rows)
  { bh8 t0 = *(const bh8*)(vi + kh), t1 = *(const bh8*)(vi + 16 + kh);
    epi_h(bepe);
    a0c = t0; a1c = t1; }

  // ===== layer 2: Kdim=384, 12 chunks. A: ks0-7 v_i, 8-15 v_j, 16-23 h1(hbuf)
  auto ldA2 = [&](int ks) -> bh8 {
    if (ks < 8)  return *(const bh8*)(vi + ks * 16 + kh);
    if (ks < 16) return *(const bh8*)(vj + ks * 16 + kh - 128);
    return *(const bh8*)(&hbuf[row * 136 + ks * 16 + kh - 256]);
  };
  #pragma unroll
  for (int h = 0; h < 6; ++h) {
    { const int c = 2 * h;      // even, <=10: always next wf2
      stage2(wf2, 24, c + 1, wbuf1);
      bh8 t0 = ldA2(2 * c + 2), t1 = ldA2(2 * c + 3);
      compute2(wbuf0, a0c, a1c);
      a0n = t0; a1n = t1;
      __syncthreads();
    }
    { const int c = 2 * h + 1;
      if (c < 11) stage2(wf2, 24, c + 1, wbuf0); else stage2(wf3, 8, 0, wbuf0);
      bh8 t0, t1;
      if (c < 11) { t0 = ldA2(2 * c + 2); t1 = ldA2(2 * c + 3); }
      compute2(wbuf1, a0n, a1n);
      if (c < 11) { a0c = t0; a1c = t1; }
      __syncthreads();
    }
  }

  // ===== L3 prologue: h2 epilogue, A ks0,1 from hbuf
  epi_h(bev1);
  a0c = *(const bh8*)(&hbuf[row * 136 + kh]);
  a1c = *(const bh8*)(&hbuf[row * 136 + 16 + kh]);

  // ===== layer 3: Kdim=128, 4 chunks, A from hbuf (h2)
  auto ldA3 = [&](int ks) -> bh8 {
    return *(const bh8*)(&hbuf[row * 136 + ks * 16 + kh]);
  };
  #pragma unroll
  for (int h = 0; h < 2; ++h) {
    { const int c = 2 * h;
      if (c < 3) stage2(wf3, 8, c + 1, wbuf1);
      bh8 t0, t1;
      if (c < 3) { t0 = ldA3(2 * c + 2); t1 = ldA3(2 * c + 3); }
      compute2(wbuf0, a0c, a1c);
      if (c < 3) { a0n = t0; a1n = t1; }
      __syncthreads();
    }
    { const int c = 2 * h + 1;
      if (c < 3) stage2(wf3, 8, c + 1, wbuf0);
      bh8 t0, t1;
      if (c < 3) { t0 = ldA3(2 * c + 2); t1 = ldA3(2 * c + 3); }
      compute2(wbuf1, a0n, a1n);
      if (c < 3) { a0c = t0; a1c = t1; }
      __syncthreads();
    }
  }

  // ===== epilogue: bias + e_value store
  #pragma unroll
  for (int ni = 0; ni < 4; ++ni) {
    int n = ni * 32 + cb;
    float bv = bev2[n];
    #pragma unroll
    for (int r = 0; r < 16; ++r) {
      int rj = rb + (r & 3) + ((r >> 2) << 3);
      acc[ni][r] += bv;
      oute[(size_t)(bi * 128 + rj) * 128 + n] = acc[ni][r];
    }
  }

  // ===== in-block aggregation: vf[n] = sum_j atten[j][n>>3]*ev[j][n] + silu_self
  // (last chunk's __syncthreads guarantees all hbuf reads done; safe to overwrite)
  float* attf = (float*)hbuf;            // [j][gl][ni] transposed, 2048 f32
  float* aggl = attf + 2048;             // [4 waves][128]
  const float* ap = atten + (size_t)bi * 2048;
  #pragma unroll
  for (int u = 0; u < 8; ++u) {
    int idx = u * 256 + tid;
    float v = ap[idx];
    int j2 = idx >> 4, g = idx & 15;
    attf[j2 * 16 + (g & 3) * 4 + (g >> 2)] = v;
  }
  float sav = 0.f;
  if (tid < 128) sav = sab[(size_t)bi * 128 + tid];
  __syncthreads();
  float p0 = 0.f, p1 = 0.f, p2 = 0.f, p3 = 0.f;
  const int gl = (l & 31) >> 3;
  #pragma unroll
  for (int r = 0; r < 16; ++r) {
    int rj = rb + (r & 3) + ((r >> 2) << 3);
    f4v av = *(const f4v*)&attf[rj * 16 + gl * 4];
    p0 += av[0] * acc[0][r]; p1 += av[1] * acc[1][r];
    p2 += av[2] * acc[2][r]; p3 += av[3] * acc[3][r];
  }
  p0 += __shfl_xor(p0, 32); p1 += __shfl_xor(p1, 32);
  p2 += __shfl_xor(p2, 32); p3 += __shfl_xor(p3, 32);
  if (l < 32) {
    aggl[w * 128 +  0 + l] = p0;
    aggl[w * 128 + 32 + l] = p1;
    aggl[w * 128 + 64 + l] = p2;
    aggl[w * 128 + 96 + l] = p3;
  }
  __syncthreads();
  if (tid < 128) {
    vfb[(size_t)bi * 128 + tid] =
        aggl[tid] + aggl[128 + tid] + aggl[256 + tid] + aggl[384 + tid] + sav;
  }
}

// ---------- max-pool over i (2 stage) ----------
__global__ void k_pool1(const float* __restrict__ vfb, float* __restrict__ pm) {
  const int b = blockIdx.x >> 3, c = blockIdx.x & 7;
  const int t = threadIdx.x;
  float m = -1e30f;
  for (int i2 = c * 16; i2 < c * 16 + 16; ++i2)
    m = fmaxf(m, vfb[(size_t)(b * 128 + i2) * 128 + t]);
  pm[(size_t)blockIdx.x * 128 + t] = m;
}
__global__ void k_pool2(const float* __restrict__ pm, float* __restrict__ pool) {
  const int b = blockIdx.x;
  const int t = threadIdx.x;
  float m = -1e30f;
  #pragma unroll
  for (int c = 0; c < 8; ++c) m = fmaxf(m, pm[(size_t)(b * 8 + c) * 128 + t]);
  pool[b * 128 + t] = m;
}

// ---------- out MLP: v_out = silu([vf|pool] @ W_out + b) ----------
__global__ __launch_bounds__(128) void k_out(
    const float* __restrict__ vfb, const float* __restrict__ pool,
    const float* __restrict__ W, const float* __restrict__ bias,
    float* __restrict__ vout) {
  __shared__ float x[4][256];
  const int r0 = blockIdx.x * 4;
  const int b  = r0 >> 7;
  const int t  = threadIdx.x;
  #pragma unroll
  for (int rr = 0; rr < 4; ++rr) {
    x[rr][t]       = vfb[(r0 + rr) * 128 + t];
    x[rr][t + 128] = pool[b * 128 + t];
  }
  __syncthreads();
  float acc[4];
  const float bv = bias[t];
  #pragma unroll
  for (int rr = 0; rr < 4; ++rr) acc[rr] = bv;
  for (int k4 = 0; k4 < 256; k4 += 4) {
    f4v xx0 = *(const f4v*)&x[0][k4];
    f4v xx1 = *(const f4v*)&x[1][k4];
    f4v xx2 = *(const f4v*)&x[2][k4];
    f4v xx3 = *(const f4v*)&x[3][k4];
    #pragma unroll
    for (int u = 0; u < 4; ++u) {
      float w = W[(k4 + u) * 128 + t];
      acc[0] += xx0[u] * w; acc[1] += xx1[u] * w;
      acc[2] += xx2[u] * w; acc[3] += xx3[u] * w;
    }
  }
  #pragma unroll
  for (int rr = 0; rr < 4; ++rr) vout[(r0 + rr) * 128 + t] = silu_f(acc[rr]);
}

extern "C" void kernel_launch(void* const* d_in, const int* in_sizes, int n_in,
                              void* d_out, int out_size, void* d_ws, size_t ws_size,
                              hipStream_t stream) {
  const float* v_f    = (const float*)d_in[0];
  const float* e_f    = (const float*)d_in[1];
  const float* p_pe   = (const float*)d_in[2];
  const float* t_pe   = (const float*)d_in[3];
  const float* W_vpe  = (const float*)d_in[4];
  const float* b_vpe  = (const float*)d_in[5];
  const float* W_epe  = (const float*)d_in[6];
  const float* b_epe  = (const float*)d_in[7];
  const float* W_ev1  = (const float*)d_in[8];
  const float* b_ev1  = (const float*)d_in[9];
  const float* W_ev2  = (const float*)d_in[10];
  const float* b_ev2  = (const float*)d_in[11];
  const float* W_q    = (const float*)d_in[12];
  const float* b_q    = (const float*)d_in[13];
  const float* W_k    = (const float*)d_in[14];
  const float* b_k    = (const float*)d_in[15];
  const float* W_self = (const float*)d_in[16];
  const float* b_self = (const float*)d_in[17];
  const float* W_out  = (const float*)d_in[18];
  const float* b_out  = (const float*)d_in[19];

  char* ws = (char*)d_ws;
  unsigned short* vb16  = (unsigned short*)(ws + 0);        // 262144
  float*          qbuf  = (float*)(ws + 262144);            // 524288
  float*          kbuf  = (float*)(ws + 786432);            // 524288
  float*          sabuf = (float*)(ws + 1310720);           // 524288
  float*          vfbuf = (float*)(ws + 1835008);           // 524288
  float*          pool  = (float*)(ws + 2359296);           // 4096
  short*          wf1   = (short*)(ws + 2363392);           // 49152
  short*          wf2   = (short*)(ws + 2412544);           // 98304
  short*          wf3   = (short*)(ws + 2510848);           // 32768
  float*          atten = (float*)(ws + 2543616);           // 8388608
  float*          pmax  = (float*)(ws + 10932224);          // 32768 -> 10.97MB

  float* v_out = (float*)d_out;
  float* out_e = (float*)d_out + 131072;

  k_wfrag3<<<352, 256, 0, stream>>>(W_epe, wf1, W_ev1, wf2, W_ev2, wf3);
  k_node<<<256, 128, 0, stream>>>(v_f, p_pe, t_pe, W_vpe, b_vpe, W_q, b_q,
                                  W_k, b_k, W_self, b_self, vb16, qbuf, kbuf, sabuf);
  k_atten<<<1024, 128, 0, stream>>>(qbuf, kbuf, atten);
  k_edge<<<1024, 256, 0, stream>>>(e_f, t_pe, vb16, wf1, wf2, wf3,
                                   b_epe, b_ev1, b_ev2, atten, sabuf, out_e, vfbuf);
  k_pool1<<<64, 128, 0, stream>>>(vfbuf, pmax);
  k_pool2<<<8, 128, 0, stream>>>(pmax, pool);
  k_out<<<256, 128, 0, stream>>>(vfbuf, pool, W_out, b_out, v_out);
}